// Round 1
// baseline (299.240 us; speedup 1.0000x reference)
//
#include <hip/hip_runtime.h>

// Problem constants
#define T_ 64
#define P_ 144          // 12*12 windows per frame
#define NPAIR 9216      // T_*P_
#define C_ 1024
#define MID_ 256
#define NKROW 36864     // NPAIR*4

typedef __attribute__((ext_vector_type(4))) float f32x4;
typedef __attribute__((ext_vector_type(8))) __bf16 bf16x8;
typedef __attribute__((ext_vector_type(4))) __bf16 bf16x4;

__device__ __forceinline__ void async_copy16(const void* g, void* l) {
  __builtin_amdgcn_global_load_lds(
      (const __attribute__((address_space(1))) unsigned int*)g,
      (__attribute__((address_space(3))) unsigned int*)l, 16, 0, 0);
}

// ---------------------------------------------------------------------------
// K1: gather 2x2 windows + mean-pool, convert to bf16.
// grid = NPAIR blocks x 256 threads; thread handles 4 channels.
__global__ void pool_convert_kernel(const float* __restrict__ img,
                                    __bf16* __restrict__ winb,
                                    __bf16* __restrict__ poolb) {
  const int pair = blockIdx.x;
  const int t = pair / P_;
  const int p = pair - t * P_;
  const int wy = p / 12, wx = p - wy * 12;
  const int c = threadIdx.x * 4;
  const float* base = img + (size_t)t * 576 * C_;
  const int r0 = 48 * wy + 2 * wx;  // (2*wy)*24 + 2*wx
  const int rows[4] = {r0, r0 + 1, r0 + 24, r0 + 25};  // w = iy*2+ix
  f32x4 s = {0.f, 0.f, 0.f, 0.f};
#pragma unroll
  for (int w = 0; w < 4; ++w) {
    f32x4 v = *(const f32x4*)(base + (size_t)rows[w] * C_ + c);
    s += v;
    bf16x4 bv;
#pragma unroll
    for (int j = 0; j < 4; ++j) bv[j] = (__bf16)v[j];
    *(bf16x4*)(winb + ((size_t)pair * 4 + w) * C_ + c) = bv;
  }
  s *= 0.25f;
  bf16x4 pv;
#pragma unroll
  for (int j = 0; j < 4; ++j) pv[j] = (__bf16)s[j];
  *(bf16x4*)(poolb + (size_t)pair * C_ + c) = pv;
}

// ---------------------------------------------------------------------------
// K2: transpose + convert weights: W [1024x256] f32 -> Wt [256x1024] bf16.
// grid = (32, 8, 2) blocks, block (32, 8).
__global__ void wtrans_kernel(const float* __restrict__ Wq,
                              const float* __restrict__ Wk,
                              __bf16* __restrict__ Wqt,
                              __bf16* __restrict__ Wkt) {
  __shared__ float t[32][33];
  const float* src = blockIdx.z ? Wk : Wq;
  __bf16* dst = blockIdx.z ? Wkt : Wqt;
  const int k0 = blockIdx.x * 32, n0 = blockIdx.y * 32;
#pragma unroll
  for (int i = 0; i < 32; i += 8) {
    t[threadIdx.y + i][threadIdx.x] =
        src[(size_t)(k0 + threadIdx.y + i) * MID_ + n0 + threadIdx.x];
  }
  __syncthreads();
#pragma unroll
  for (int i = 0; i < 32; i += 8) {
    dst[(size_t)(n0 + threadIdx.y + i) * C_ + k0 + threadIdx.x] =
        (__bf16)t[threadIdx.x][threadIdx.y + i];
  }
}

// ---------------------------------------------------------------------------
// K3: merged GEMM.  Q[9216x256] = pooled@Wq + bq  (blocks 0..143)
//                   K[36864x256] = windows@Wk + bk (blocks 144..719)
// 128x128 tile, BK=32, 4 waves in 2x2, 4x4 frags of mfma_f32_16x16x32_bf16.
__global__ __launch_bounds__(256) void gemm_qk_kernel(
    const __bf16* __restrict__ Apool, const __bf16* __restrict__ Awin,
    const __bf16* __restrict__ Bqt, const __bf16* __restrict__ Bkt,
    const float* __restrict__ bq, const float* __restrict__ bk,
    float* __restrict__ Qo, float* __restrict__ Ko) {
  __shared__ __align__(16) __bf16 As[128 * 32];
  __shared__ __align__(16) __bf16 Bs[128 * 32];
  const int bid = blockIdx.x;
  const __bf16* A;
  const __bf16* Bt;
  const float* bias;
  float* Cout;
  int mt, nt;
  if (bid < 144) {
    A = Apool; Bt = Bqt; bias = bq; Cout = Qo;
    mt = bid >> 1; nt = bid & 1;
  } else {
    const int b = bid - 144;
    A = Awin; Bt = Bkt; bias = bk; Cout = Ko;
    mt = b >> 1; nt = b & 1;
  }
  const int tid = threadIdx.x;
  const int lane = tid & 63;
  const int wv = tid >> 6;
  const int quad = lane >> 4, lr = lane & 15;
  const int wm = wv >> 1, wn = wv & 1;

  // staging: 512 chunks of 16B per tile; thread covers chunk tid and tid+256
  const int r0 = tid >> 2, p0 = tid & 3;
  const __bf16* ga0 = A + ((size_t)mt * 128 + r0) * (size_t)C_ + p0 * 8;
  const __bf16* ga1 = ga0 + (size_t)64 * C_;
  const __bf16* gb0 = Bt + ((size_t)nt * 128 + r0) * (size_t)C_ + p0 * 8;
  const __bf16* gb1 = gb0 + (size_t)64 * C_;
  const int wvb = (tid & ~63) * 16;  // wave-uniform LDS byte offset
  char* AsB0 = (char*)As + wvb;
  char* AsB1 = (char*)As + 4096 + wvb;
  char* BsB0 = (char*)Bs + wvb;
  char* BsB1 = (char*)Bs + 4096 + wvb;

  f32x4 acc[4][4] = {};

  for (int it = 0; it < 32; ++it) {
    async_copy16(ga0, AsB0);
    async_copy16(ga1, AsB1);
    async_copy16(gb0, BsB0);
    async_copy16(gb1, BsB1);
    ga0 += 32; ga1 += 32; gb0 += 32; gb1 += 32;
    __syncthreads();  // drains vmcnt before barrier -> LDS tile visible

    bf16x8 a[4], b[4];
    const bf16x8* Ap = (const bf16x8*)As;
    const bf16x8* Bp = (const bf16x8*)Bs;
#pragma unroll
    for (int i = 0; i < 4; ++i) {
      a[i] = Ap[(wm * 64 + i * 16 + lr) * 4 + quad];
      b[i] = Bp[(wn * 64 + i * 16 + lr) * 4 + quad];
    }
#pragma unroll
    for (int mi = 0; mi < 4; ++mi)
#pragma unroll
      for (int ni = 0; ni < 4; ++ni)
        acc[mi][ni] = __builtin_amdgcn_mfma_f32_16x16x32_bf16(
            a[mi], b[ni], acc[mi][ni], 0, 0, 0);
    __syncthreads();
  }

  // epilogue: C/D layout col=lane&15, row=quad*4+reg (verified mapping)
  const int colb = nt * 128 + wn * 64;
  const int rowb = mt * 128 + wm * 64 + quad * 4;
#pragma unroll
  for (int ni = 0; ni < 4; ++ni) {
    const int col = colb + ni * 16 + lr;
    const float bv = bias[col];
#pragma unroll
    for (int mi = 0; mi < 4; ++mi) {
      const int row = rowb + mi * 16;
#pragma unroll
      for (int r = 0; r < 4; ++r)
        Cout[(size_t)(row + r) * MID_ + col] = acc[mi][ni][r] + bv;
    }
  }
}

// ---------------------------------------------------------------------------
// K4: per-(t,p) epilogue: 4 dots over MID=256, softmax over 4, weighted sum.
// grid = NPAIR blocks x 256 threads.
__global__ void attn_epilogue_kernel(const float* __restrict__ Qm,
                                     const float* __restrict__ Km,
                                     const __bf16* __restrict__ winb,
                                     const __bf16* __restrict__ poolb,
                                     float* __restrict__ out) {
  const int pair = blockIdx.x;
  const int tid = threadIdx.x;
  const int wv = tid >> 6, lane = tid & 63;
  __shared__ float red[4][4];
  const float qv = Qm[(size_t)pair * MID_ + tid];
#pragma unroll
  for (int w = 0; w < 4; ++w) {
    float p = qv * Km[((size_t)pair * 4 + w) * MID_ + tid];
    p += __shfl_down(p, 32);
    p += __shfl_down(p, 16);
    p += __shfl_down(p, 8);
    p += __shfl_down(p, 4);
    p += __shfl_down(p, 2);
    p += __shfl_down(p, 1);
    if (lane == 0) red[w][wv] = p;
  }
  __syncthreads();
  float lg[4];
  float mx = -1e30f;
#pragma unroll
  for (int w = 0; w < 4; ++w) {
    lg[w] = (red[w][0] + red[w][1] + red[w][2] + red[w][3]) * 0.0625f;
    mx = fmaxf(mx, lg[w]);
  }
  float att[4];
  float ssum = 0.f;
#pragma unroll
  for (int w = 0; w < 4; ++w) {
    att[w] = __expf(lg[w] - mx);
    ssum += att[w];
  }
  const float inv = 1.f / ssum;

  const int c = tid * 4;
  const bf16x4 pv = *(const bf16x4*)(poolb + (size_t)pair * C_ + c);
  f32x4 o;
#pragma unroll
  for (int j = 0; j < 4; ++j) o[j] = (float)pv[j];
#pragma unroll
  for (int w = 0; w < 4; ++w) {
    const float aw = att[w] * inv;
    const bf16x4 wvv = *(const bf16x4*)(winb + ((size_t)pair * 4 + w) * C_ + c);
#pragma unroll
    for (int j = 0; j < 4; ++j) o[j] += aw * (float)wvv[j];
  }
  *(f32x4*)(out + (size_t)pair * C_ + c) = o;
}

// ---------------------------------------------------------------------------
extern "C" void kernel_launch(void* const* d_in, const int* in_sizes, int n_in,
                              void* d_out, int out_size, void* d_ws,
                              size_t ws_size, hipStream_t stream) {
  const float* img = (const float*)d_in[0];
  const float* Wq = (const float*)d_in[1];
  const float* bq = (const float*)d_in[2];
  const float* Wk = (const float*)d_in[3];
  const float* bk = (const float*)d_in[4];
  float* out = (float*)d_out;

  // workspace layout (total 142,606,336 B)
  char* ws = (char*)d_ws;
  __bf16* winb = (__bf16*)ws;                       // 36864*1024*2 = 75,497,472
  __bf16* poolb = (__bf16*)(ws + 75497472);         //  9216*1024*2 = 18,874,368
  __bf16* Wqt = (__bf16*)(ws + 94371840);           //   256*1024*2 =    524,288
  __bf16* Wkt = (__bf16*)(ws + 94896128);           //   256*1024*2 =    524,288
  float* Qo = (float*)(ws + 95420416);              //  9216*256*4  =  9,437,184
  float* Ko = (float*)(ws + 104857600);             // 36864*256*4  = 37,748,736

  pool_convert_kernel<<<NPAIR, 256, 0, stream>>>(img, winb, poolb);
  wtrans_kernel<<<dim3(32, 8, 2), dim3(32, 8, 1), 0, stream>>>(Wq, Wk, Wqt, Wkt);
  gemm_qk_kernel<<<720, 256, 0, stream>>>(poolb, winb, Wqt, Wkt, bq, bk, Qo, Ko);
  attn_epilogue_kernel<<<NPAIR, 256, 0, stream>>>(Qo, Ko, winb, poolb, out);
}